// Round 1
// baseline (798.905 us; speedup 1.0000x reference)
//
#include <hip/hip_runtime.h>

#define NC 24  // N*C = 8*3

// ---------- pyrDown: 5x5 binomial /256, reflect-101 pad 2, stride 2 ----------
// Linear with unit-sum kernel => optional affine (scale,offs) applied at output
// implements img = x*255+1 for the first level.
__global__ void pyrdown_kernel(const float* __restrict__ in, float* __restrict__ out,
                               int Hi, int Wi, int Ho, int Wo, float scale, float offs)
{
    int ox = blockIdx.x * blockDim.x + threadIdx.x;
    int oy = blockIdx.y * blockDim.y + threadIdx.y;
    int nc = blockIdx.z;
    if (ox >= Wo || oy >= Ho) return;
    const float* ip = in + (size_t)nc * Hi * Wi;
    const float k1[5] = {0.0625f, 0.25f, 0.375f, 0.25f, 0.0625f};
    float acc = 0.f;
#pragma unroll
    for (int i = 0; i < 5; ++i) {
        int y = 2 * oy - 2 + i;
        y = (y < 0) ? -y : y;
        y = (y >= Hi) ? (2 * Hi - 2 - y) : y;
        const float* rp = ip + (size_t)y * Wi;
        float r = 0.f;
#pragma unroll
        for (int j = 0; j < 5; ++j) {
            int xx = 2 * ox - 2 + j;
            xx = (xx < 0) ? -xx : xx;
            xx = (xx >= Wi) ? (2 * Wi - 2 - xx) : xx;
            r = fmaf(k1[j], rp[xx], r);
        }
        acc = fmaf(k1[i], r, acc);
    }
    out[(size_t)nc * Ho * Wo + (size_t)oy * Wo + ox] = fmaf(acc, scale, offs);
}

// ---------- Gaussian blur KxK, sigma per reference, reflect-101 ----------
template <int K>
__global__ void blur_kernel(const float* __restrict__ in, float* __restrict__ out,
                            int H, int W, float sigma)
{
    int ox = blockIdx.x * blockDim.x + threadIdx.x;
    int oy = blockIdx.y * blockDim.y + threadIdx.y;
    int nc = blockIdx.z;
    if (ox >= W || oy >= H) return;
    float w[K];
    const float c = (K - 1) * 0.5f;
    float s2 = 2.f * sigma * sigma;
    float wsum = 0.f;
#pragma unroll
    for (int i = 0; i < K; ++i) { float d = (float)i - c; w[i] = expf(-(d * d) / s2); wsum += w[i]; }
#pragma unroll
    for (int i = 0; i < K; ++i) w[i] /= wsum;
    const int R = K / 2;
    const float* ip = in + (size_t)nc * H * W;
    float acc = 0.f;
#pragma unroll
    for (int i = 0; i < K; ++i) {
        int y = oy - R + i;
        y = (y < 0) ? -y : y;
        y = (y >= H) ? (2 * H - 2 - y) : y;
        const float* rp = ip + (size_t)y * W;
        float r = 0.f;
#pragma unroll
        for (int j = 0; j < K; ++j) {
            int xx = ox - R + j;
            xx = (xx < 0) ? -xx : xx;
            xx = (xx >= W) ? (2 * W - 2 - xx) : xx;
            r = fmaf(w[j], rp[xx], r);
        }
        acc = fmaf(w[i], r, acc);
    }
    out[(size_t)nc * H * W + (size_t)oy * W + ox] = acc;
}

// ---------- 2x bilinear upsample (half-pixel, edge clamp), batched up to 3 tensors ----------
__global__ void up2_kernel(const float* __restrict__ i0, const float* __restrict__ i1,
                           const float* __restrict__ i2,
                           float* __restrict__ o0, float* __restrict__ o1, float* __restrict__ o2,
                           int Hi, int Wi)
{
    int ox = blockIdx.x * blockDim.x + threadIdx.x;
    int oy = blockIdx.y * blockDim.y + threadIdx.y;
    int z = blockIdx.z;           // t * NC + nc
    int t = z / NC, nc = z - t * NC;
    int Ho = 2 * Hi, Wo = 2 * Wi;
    if (ox >= Wo || oy >= Ho) return;
    const float* in = (t == 0) ? i0 : (t == 1) ? i1 : i2;
    float* out = (t == 0) ? o0 : (t == 1) ? o1 : o2;
    const float* ip = in + (size_t)nc * Hi * Wi;
    int my = oy >> 1, py = oy & 1;
    int mx = ox >> 1, px = ox & 1;
    int ya = py ? my : (my > 0 ? my - 1 : 0);
    int yb = py ? (my + 1 < Hi ? my + 1 : Hi - 1) : my;
    float wya = py ? 0.75f : 0.25f;
    float wyb = py ? 0.25f : 0.75f;
    int xa = px ? mx : (mx > 0 ? mx - 1 : 0);
    int xb = px ? (mx + 1 < Wi ? mx + 1 : Wi - 1) : mx;
    float wxa = px ? 0.75f : 0.25f;
    float wxb = px ? 0.25f : 0.75f;
    float v = wya * (wxa * ip[(size_t)ya * Wi + xa] + wxb * ip[(size_t)ya * Wi + xb]) +
              wyb * (wxa * ip[(size_t)yb * Wi + xa] + wxb * ip[(size_t)yb * Wi + xb]);
    out[(size_t)nc * Ho * Wo + (size_t)oy * Wo + ox] = v;
}

// ---------- final: fused 4x upsample (composed 2x∘2x, 3-tap) + MSR elementwise ----------
__global__ void final_kernel(const float* __restrict__ x,
                             const float* __restrict__ f30,
                             const float* __restrict__ f150,
                             const float* __restrict__ f300,
                             float* __restrict__ out)
{
    const int H = 1280, W = 1280, Hs = 320, Ws = 320;
    int idx = blockIdx.x * blockDim.x + threadIdx.x;  // over N*H*W
    if (idx >= 8 * H * W) return;
    int n = idx / (H * W);
    int rem = idx - n * (H * W);
    int y = rem / W;
    int xc = rem - y * W;

    // composed 4x bilinear (two chained half-pixel 2x upsamples), 3 taps/axis
    const float W4[4][3] = {{0.375f, 0.625f, 0.f},
                            {0.1875f, 0.75f, 0.0625f},
                            {0.0625f, 0.75f, 0.1875f},
                            {0.f, 0.625f, 0.375f}};
    int my = y >> 2, qy = y & 3;
    int mx = xc >> 2, qx = xc & 3;
    float wy0 = W4[qy][0], wy1 = W4[qy][1], wy2 = W4[qy][2];
    float wx0 = W4[qx][0], wx1 = W4[qx][1], wx2 = W4[qx][2];
    int ry[3], rx[3];
#pragma unroll
    for (int i = 0; i < 3; ++i) {
        int t = my - 1 + i; ry[i] = t < 0 ? 0 : (t >= Hs ? Hs - 1 : t);
        t = mx - 1 + i;     rx[i] = t < 0 ? 0 : (t >= Ws ? Ws - 1 : t);
    }

    const float* fptr[3] = {f30, f150, f300};
    float img[3];
    float img_sum = 0.f;
#pragma unroll
    for (int c = 0; c < 3; ++c) {
        img[c] = x[((size_t)(n * 3 + c) * H + y) * W + xc] * 255.f + 1.f;
        img_sum += img[c];
    }
#pragma unroll
    for (int c = 0; c < 3; ++c) {
        float sumlog = 0.f;
#pragma unroll
        for (int s = 0; s < 3; ++s) {
            const float* fp = fptr[s] + (size_t)(n * 3 + c) * Hs * Ws;
            const float* r0 = fp + (size_t)ry[0] * Ws;
            const float* r1 = fp + (size_t)ry[1] * Ws;
            const float* r2 = fp + (size_t)ry[2] * Ws;
            float acc = wy0 * (wx0 * r0[rx[0]] + wx1 * r0[rx[1]] + wx2 * r0[rx[2]]) +
                        wy1 * (wx0 * r1[rx[0]] + wx1 * r1[rx[1]] + wx2 * r1[rx[2]]) +
                        wy2 * (wx0 * r2[rx[0]] + wx1 * r2[rx[1]] + wx2 * r2[rx[2]]);
            sumlog += __log10f(acc + 1e-6f);
        }
        float retinex = __log10f(img[c] + 1e-6f) - sumlog * (1.f / 3.f);
        float color = __log10f(img[c] * 2.f / (img_sum + 1e-6f) + 1.f);
        float e = retinex * color * 2700.f + 128.f;
        e = fminf(fmaxf(e, 0.f), 255.f);
        out[((size_t)(n * 3 + c) * H + y) * W + xc] = e * (1.f / 255.f);
    }
}

extern "C" void kernel_launch(void* const* d_in, const int* in_sizes, int n_in,
                              void* d_out, int out_size, void* d_ws, size_t ws_size,
                              hipStream_t stream)
{
    const float* x = (const float*)d_in[0];
    float* out = (float*)d_out;
    float* ws = (float*)d_ws;

    size_t off = 0;
    auto alloc = [&](int d) { float* p = ws + off; off += (size_t)NC * d * d; return p; };
    // pyramid of img = x*255+1
    float* L1 = alloc(640);
    float* L2 = alloc(320);
    float* L3 = alloc(160);
    float* L4 = alloc(80);
    float* L5 = alloc(40);
    float* L6 = alloc(20);
    float* L7 = alloc(10);
    float* L8 = alloc(5);
    // blurred bases
    float* b30  = alloc(40);   // gauss7(L5), sigma 1.4
    float* b150 = alloc(10);   // gauss9(L7), sigma 1.7
    float* b300 = alloc(5);    // gauss9(L8), sigma 1.7
    // upsample chains (stop at 320; last two doublings fused into final)
    float* u30_80  = alloc(80);  float* u30_160  = alloc(160); float* u30_320  = alloc(320);
    float* u150_20 = alloc(20);  float* u150_40  = alloc(40);  float* u150_80  = alloc(80);
    float* u150_160 = alloc(160); float* u150_320 = alloc(320);
    float* u300_10 = alloc(10);  float* u300_20  = alloc(20);  float* u300_40  = alloc(40);
    float* u300_80 = alloc(80);  float* u300_160 = alloc(160); float* u300_320 = alloc(320);
    (void)ws_size; (void)in_sizes; (void)n_in; (void)out_size;

    dim3 blk(32, 8, 1);
    auto grid2 = [&](int Wo, int Ho, int z) { return dim3((Wo + 31) / 32, (Ho + 7) / 8, z); };

    // ---- pyramid down chain ----
    pyrdown_kernel<<<grid2(640, 640, NC), blk, 0, stream>>>(x,  L1, 1280, 1280, 640, 640, 255.f, 1.f);
    pyrdown_kernel<<<grid2(320, 320, NC), blk, 0, stream>>>(L1, L2, 640, 640, 320, 320, 1.f, 0.f);
    pyrdown_kernel<<<grid2(160, 160, NC), blk, 0, stream>>>(L2, L3, 320, 320, 160, 160, 1.f, 0.f);
    pyrdown_kernel<<<grid2(80,  80,  NC), blk, 0, stream>>>(L3, L4, 160, 160, 80,  80,  1.f, 0.f);
    pyrdown_kernel<<<grid2(40,  40,  NC), blk, 0, stream>>>(L4, L5, 80,  80,  40,  40,  1.f, 0.f);
    pyrdown_kernel<<<grid2(20,  20,  NC), blk, 0, stream>>>(L5, L6, 40,  40,  20,  20,  1.f, 0.f);
    pyrdown_kernel<<<grid2(10,  10,  NC), blk, 0, stream>>>(L6, L7, 20,  20,  10,  10,  1.f, 0.f);
    pyrdown_kernel<<<grid2(5,   5,   NC), blk, 0, stream>>>(L7, L8, 10,  10,  5,   5,   1.f, 0.f);

    // ---- blurs at recursion base (ksize from sigma schedule: 7@L5, 9@L7, 9@L8) ----
    blur_kernel<7><<<grid2(40, 40, NC), blk, 0, stream>>>(L5, b30, 40, 40, 1.4f);
    blur_kernel<9><<<grid2(10, 10, NC), blk, 0, stream>>>(L7, b150, 10, 10, 1.7f);
    blur_kernel<9><<<grid2(5,  5,  NC), blk, 0, stream>>>(L8, b300, 5, 5, 1.7f);

    // ---- upsample chains (batched across sigmas at matching sizes) ----
    up2_kernel<<<grid2(10, 10, 1 * NC), blk, 0, stream>>>(b300, nullptr, nullptr,
                                                          u300_10, nullptr, nullptr, 5, 5);
    up2_kernel<<<grid2(20, 20, 2 * NC), blk, 0, stream>>>(b150, u300_10, nullptr,
                                                          u150_20, u300_20, nullptr, 10, 10);
    up2_kernel<<<grid2(40, 40, 2 * NC), blk, 0, stream>>>(u150_20, u300_20, nullptr,
                                                          u150_40, u300_40, nullptr, 20, 20);
    up2_kernel<<<grid2(80, 80, 3 * NC), blk, 0, stream>>>(b30, u150_40, u300_40,
                                                          u30_80, u150_80, u300_80, 40, 40);
    up2_kernel<<<grid2(160, 160, 3 * NC), blk, 0, stream>>>(u30_80, u150_80, u300_80,
                                                            u30_160, u150_160, u300_160, 80, 80);
    up2_kernel<<<grid2(320, 320, 3 * NC), blk, 0, stream>>>(u30_160, u150_160, u300_160,
                                                            u30_320, u150_320, u300_320, 160, 160);

    // ---- fused final: 4x upsample of the 320-level images + MSR math ----
    final_kernel<<<dim3(51200, 1, 1), dim3(256, 1, 1), 0, stream>>>(x, u30_320, u150_320, u300_320, out);
}

// Round 2
// 449.863 us; speedup vs baseline: 1.7759x; 1.7759x over previous
//
#include <hip/hip_runtime.h>

#define NC 24  // N*C = 8*3

// ---------- scalar pyrDown point: 5x5 binomial, reflect-101 ----------
__device__ __forceinline__ float pyr_point(const float* __restrict__ ip,
                                           int Hi, int Wi, int oy, int ox)
{
    const float k1[5] = {0.0625f, 0.25f, 0.375f, 0.25f, 0.0625f};
    float acc = 0.f;
#pragma unroll
    for (int i = 0; i < 5; ++i) {
        int y = 2 * oy - 2 + i;
        y = (y < 0) ? -y : y;
        y = (y >= Hi) ? (2 * Hi - 2 - y) : y;
        const float* rp = ip + (size_t)y * Wi;
        float r = 0.f;
#pragma unroll
        for (int j = 0; j < 5; ++j) {
            int xx = 2 * ox - 2 + j;
            xx = (xx < 0) ? -xx : xx;
            xx = (xx >= Wi) ? (2 * Wi - 2 - xx) : xx;
            r = fmaf(k1[j], rp[xx], r);
        }
        acc = fmaf(k1[i], r, acc);
    }
    return acc;
}

// ---------- scalar pyrDown kernel (tiny tail levels) ----------
__global__ void pyrdown_kernel(const float* __restrict__ in, float* __restrict__ out,
                               int Hi, int Wi, int Ho, int Wo, float scale, float offs)
{
    int ox = blockIdx.x * blockDim.x + threadIdx.x;
    int oy = blockIdx.y * blockDim.y + threadIdx.y;
    int nc = blockIdx.z;
    if (ox >= Wo || oy >= Ho) return;
    const float* ip = in + (size_t)nc * Hi * Wi;
    out[((size_t)nc * Ho + oy) * Wo + ox] = fmaf(pyr_point(ip, Hi, Wi, oy, ox), scale, offs);
}

// ---------- pyrDown, 4 outputs/thread, float4 interior fast path ----------
__global__ void __launch_bounds__(256) pyrdown4_kernel(
    const float* __restrict__ in, float* __restrict__ out,
    int Hi, int Wi, int Ho, int Wo, float scale, float offs)
{
    int qx = blockIdx.x * blockDim.x + threadIdx.x;  // output quad index
    int oy = blockIdx.y * blockDim.y + threadIdx.y;
    int nc = blockIdx.z;
    int ox0 = qx * 4;
    if (ox0 >= Wo || oy >= Ho) return;
    const float* ip = in + (size_t)nc * Hi * Wi;
    const float k[5] = {0.0625f, 0.25f, 0.375f, 0.25f, 0.0625f};

    bool fastx = (qx >= 1) && (8 * qx + 11 <= Wi - 1) && (ox0 + 3 < Wo);
    bool fasty = (oy >= 1) && (2 * oy + 2 <= Hi - 1);
    if (fastx && fasty) {
        int x0 = 8 * qx - 4;  // float4-aligned base; needed cols are rel [2,12]
        float col[11];
#pragma unroll
        for (int j = 0; j < 11; ++j) col[j] = 0.f;
        const float* rp = ip + (size_t)(2 * oy - 2) * Wi + x0;
#pragma unroll
        for (int i = 0; i < 5; ++i) {
            float4 a = *(const float4*)(rp);
            float4 b = *(const float4*)(rp + 4);
            float4 c4 = *(const float4*)(rp + 8);
            float4 d = *(const float4*)(rp + 12);
            float rv[16] = {a.x, a.y, a.z, a.w, b.x, b.y, b.z, b.w,
                            c4.x, c4.y, c4.z, c4.w, d.x, d.y, d.z, d.w};
#pragma unroll
            for (int j = 0; j < 11; ++j) col[j] = fmaf(k[i], rv[j + 2], col[j]);
            rp += Wi;
        }
        float4 o;
        float* op = (float*)&o;
#pragma unroll
        for (int p = 0; p < 4; ++p) {
            float s = 0.f;
#pragma unroll
            for (int j = 0; j < 5; ++j) s = fmaf(k[j], col[2 * p + j], s);
            op[p] = fmaf(s, scale, offs);
        }
        *(float4*)&out[((size_t)nc * Ho + oy) * Wo + ox0] = o;
    } else {
#pragma unroll
        for (int p = 0; p < 4; ++p) {
            int ox = ox0 + p;
            if (ox < Wo)
                out[((size_t)nc * Ho + oy) * Wo + ox] =
                    fmaf(pyr_point(ip, Hi, Wi, oy, ox), scale, offs);
        }
    }
}

// ---------- Gaussian blur KxK, reflect-101 ----------
template <int K>
__global__ void blur_kernel(const float* __restrict__ in, float* __restrict__ out,
                            int H, int W, float sigma)
{
    int ox = blockIdx.x * blockDim.x + threadIdx.x;
    int oy = blockIdx.y * blockDim.y + threadIdx.y;
    int nc = blockIdx.z;
    if (ox >= W || oy >= H) return;
    float w[K];
    const float c = (K - 1) * 0.5f;
    float s2 = 2.f * sigma * sigma;
    float wsum = 0.f;
#pragma unroll
    for (int i = 0; i < K; ++i) { float d = (float)i - c; w[i] = expf(-(d * d) / s2); wsum += w[i]; }
#pragma unroll
    for (int i = 0; i < K; ++i) w[i] /= wsum;
    const int R = K / 2;
    const float* ip = in + (size_t)nc * H * W;
    float acc = 0.f;
#pragma unroll
    for (int i = 0; i < K; ++i) {
        int y = oy - R + i;
        y = (y < 0) ? -y : y;
        y = (y >= H) ? (2 * H - 2 - y) : y;
        const float* rp = ip + (size_t)y * W;
        float r = 0.f;
#pragma unroll
        for (int j = 0; j < K; ++j) {
            int xx = ox - R + j;
            xx = (xx < 0) ? -xx : xx;
            xx = (xx >= W) ? (2 * W - 2 - xx) : xx;
            r = fmaf(w[j], rp[xx], r);
        }
        acc = fmaf(w[i], r, acc);
    }
    out[((size_t)nc * H + oy) * W + ox] = acc;
}

// ---------- 2x bilinear upsample (half-pixel, edge clamp), batched ----------
__global__ void up2_kernel(const float* __restrict__ i0, const float* __restrict__ i1,
                           const float* __restrict__ i2,
                           float* __restrict__ o0, float* __restrict__ o1, float* __restrict__ o2,
                           int Hi, int Wi)
{
    int ox = blockIdx.x * blockDim.x + threadIdx.x;
    int oy = blockIdx.y * blockDim.y + threadIdx.y;
    int z = blockIdx.z;           // t * NC + nc
    int t = z / NC, nc = z - t * NC;
    int Ho = 2 * Hi, Wo = 2 * Wi;
    if (ox >= Wo || oy >= Ho) return;
    const float* in = (t == 0) ? i0 : (t == 1) ? i1 : i2;
    float* out = (t == 0) ? o0 : (t == 1) ? o1 : o2;
    const float* ip = in + (size_t)nc * Hi * Wi;
    int my = oy >> 1, py = oy & 1;
    int mx = ox >> 1, px = ox & 1;
    int ya = py ? my : (my > 0 ? my - 1 : 0);
    int yb = py ? (my + 1 < Hi ? my + 1 : Hi - 1) : my;
    float wya = py ? 0.75f : 0.25f;
    float wyb = py ? 0.25f : 0.75f;
    int xa = px ? mx : (mx > 0 ? mx - 1 : 0);
    int xb = px ? (mx + 1 < Wi ? mx + 1 : Wi - 1) : mx;
    float wxa = px ? 0.75f : 0.25f;
    float wxb = px ? 0.25f : 0.75f;
    float v = wya * (wxa * ip[(size_t)ya * Wi + xa] + wxb * ip[(size_t)ya * Wi + xb]) +
              wyb * (wxa * ip[(size_t)yb * Wi + xa] + wxb * ip[(size_t)yb * Wi + xb]);
    out[((size_t)nc * Ho + oy) * Wo + ox] = v;
}

// ---------- final: 4x4 block per thread, fused 4x upsample + MSR ----------
__global__ void __launch_bounds__(256) final_kernel(
    const float* __restrict__ x,
    const float* __restrict__ f30,
    const float* __restrict__ f150,
    const float* __restrict__ f300,
    float* __restrict__ out)
{
    const int H = 1280, W = 1280, Hs = 320, Ws = 320;
    int t = blockIdx.x * 256 + threadIdx.x;          // over 8 * 320 * 320 blocks
    if (t >= 8 * Hs * Ws) return;
    int n = t / (Hs * Ws);
    int r = t - n * (Hs * Ws);
    int by = r / Ws;
    int bx = r - by * Ws;

    // composed 4x bilinear taps: center = (by,bx), neighbors clamped
    int ry[3], rx[3];
    ry[0] = by > 0 ? by - 1 : 0; ry[1] = by; ry[2] = by < Hs - 1 ? by + 1 : Hs - 1;
    rx[0] = bx > 0 ? bx - 1 : 0; rx[1] = bx; rx[2] = bx < Ws - 1 ? bx + 1 : Ws - 1;
    const float WP[4][3] = {{0.375f, 0.625f, 0.f},
                            {0.1875f, 0.75f, 0.0625f},
                            {0.0625f, 0.75f, 0.1875f},
                            {0.f, 0.625f, 0.375f}};

    // load x: 3 channels x 4 rows of float4
    float4 xi[3][4];
#pragma unroll
    for (int c = 0; c < 3; ++c)
#pragma unroll
        for (int qy = 0; qy < 4; ++qy)
            xi[c][qy] = *(const float4*)&x[((size_t)(n * 3 + c) * H + 4 * by + qy) * W + 4 * bx];

    // 2/(img_sum+eps) per pixel
    float crcp[4][4];
#pragma unroll
    for (int qy = 0; qy < 4; ++qy) {
        const float* p0 = (const float*)&xi[0][qy];
        const float* p1 = (const float*)&xi[1][qy];
        const float* p2 = (const float*)&xi[2][qy];
#pragma unroll
        for (int qx = 0; qx < 4; ++qx) {
            float s = (p0[qx] + p1[qx] + p2[qx]) * 255.f + 3.f;
            crcp[qy][qx] = __fdividef(2.f, s + 1e-6f);
        }
    }

    const float* F[3] = {f30, f150, f300};
#pragma unroll
    for (int c = 0; c < 3; ++c) {
        float prod[4][4];
#pragma unroll
        for (int qy = 0; qy < 4; ++qy)
#pragma unroll
            for (int qx = 0; qx < 4; ++qx) prod[qy][qx] = 1.f;

#pragma unroll
        for (int s = 0; s < 3; ++s) {
            const float* fp = F[s] + (size_t)(n * 3 + c) * Hs * Ws;
            float v[3][3];
#pragma unroll
            for (int i = 0; i < 3; ++i)
#pragma unroll
                for (int j = 0; j < 3; ++j) v[i][j] = fp[(size_t)ry[i] * Ws + rx[j]];
#pragma unroll
            for (int qy = 0; qy < 4; ++qy) {
                float vy0 = WP[qy][0] * v[0][0] + WP[qy][1] * v[1][0] + WP[qy][2] * v[2][0];
                float vy1 = WP[qy][0] * v[0][1] + WP[qy][1] * v[1][1] + WP[qy][2] * v[2][1];
                float vy2 = WP[qy][0] * v[0][2] + WP[qy][1] * v[1][2] + WP[qy][2] * v[2][2];
#pragma unroll
                for (int qx = 0; qx < 4; ++qx) {
                    float val = WP[qx][0] * vy0 + WP[qx][1] * vy1 + WP[qx][2] * vy2;
                    prod[qy][qx] *= (val + 1e-6f);
                }
            }
        }

#pragma unroll
        for (int qy = 0; qy < 4; ++qy) {
            const float* xp = (const float*)&xi[c][qy];
            float4 o;
            float* op = (float*)&o;
#pragma unroll
            for (int qx = 0; qx < 4; ++qx) {
                float img = xp[qx] * 255.f + 1.f;
                float a = img + 1e-6f;
                // retinex*color*2700: retinex = log10(a^3/prod)/3, color = log10(carg)
                // folded: l2a * l2c * (2700/3 * log10(2)^2)
                float l2a = __log2f(__fdividef(a * a * a, prod[qy][qx]));
                float carg = fmaf(img, crcp[qy][qx], 1.f);
                float l2c = __log2f(carg);
                float e = fmaf(l2a * l2c, 81.55715246f, 128.f);
                e = fminf(fmaxf(e, 0.f), 255.f);
                op[qx] = e * (1.f / 255.f);
            }
            *(float4*)&out[((size_t)(n * 3 + c) * H + 4 * by + qy) * W + 4 * bx] = o;
        }
    }
}

extern "C" void kernel_launch(void* const* d_in, const int* in_sizes, int n_in,
                              void* d_out, int out_size, void* d_ws, size_t ws_size,
                              hipStream_t stream)
{
    const float* x = (const float*)d_in[0];
    float* out = (float*)d_out;
    float* ws = (float*)d_ws;

    size_t off = 0;
    auto alloc = [&](int d) { float* p = ws + off; off += (size_t)NC * d * d; return p; };
    float* L1 = alloc(640);
    float* L2 = alloc(320);
    float* L3 = alloc(160);
    float* L4 = alloc(80);
    float* L5 = alloc(40);
    float* L6 = alloc(20);
    float* L7 = alloc(10);
    float* L8 = alloc(5);
    float* b30  = alloc(40);
    float* b150 = alloc(10);
    float* b300 = alloc(5);
    float* u30_80  = alloc(80);  float* u30_160  = alloc(160); float* u30_320  = alloc(320);
    float* u150_20 = alloc(20);  float* u150_40  = alloc(40);  float* u150_80  = alloc(80);
    float* u150_160 = alloc(160); float* u150_320 = alloc(320);
    float* u300_10 = alloc(10);  float* u300_20  = alloc(20);  float* u300_40  = alloc(40);
    float* u300_80 = alloc(80);  float* u300_160 = alloc(160); float* u300_320 = alloc(320);
    (void)ws_size; (void)in_sizes; (void)n_in; (void)out_size;

    dim3 blk(32, 8, 1);
    auto grid2 = [&](int Wo, int Ho, int z) { return dim3((Wo + 31) / 32, (Ho + 7) / 8, z); };
    auto grid4 = [&](int Wo, int Ho) { return dim3((Wo / 4 + 31) / 32, (Ho + 7) / 8, NC); };

    // ---- pyramid down chain (vectorized kernel for all but tiny tail) ----
    pyrdown4_kernel<<<grid4(640, 640), blk, 0, stream>>>(x,  L1, 1280, 1280, 640, 640, 255.f, 1.f);
    pyrdown4_kernel<<<grid4(320, 320), blk, 0, stream>>>(L1, L2, 640, 640, 320, 320, 1.f, 0.f);
    pyrdown4_kernel<<<grid4(160, 160), blk, 0, stream>>>(L2, L3, 320, 320, 160, 160, 1.f, 0.f);
    pyrdown4_kernel<<<grid4(80,  80),  blk, 0, stream>>>(L3, L4, 160, 160, 80,  80,  1.f, 0.f);
    pyrdown4_kernel<<<grid4(40,  40),  blk, 0, stream>>>(L4, L5, 80,  80,  40,  40,  1.f, 0.f);
    pyrdown4_kernel<<<grid4(20,  20),  blk, 0, stream>>>(L5, L6, 40,  40,  20,  20,  1.f, 0.f);
    pyrdown_kernel<<<grid2(10, 10, NC), blk, 0, stream>>>(L6, L7, 20, 20, 10, 10, 1.f, 0.f);
    pyrdown_kernel<<<grid2(5,  5,  NC), blk, 0, stream>>>(L7, L8, 10, 10, 5,  5,  1.f, 0.f);

    // ---- blurs at recursion base ----
    blur_kernel<7><<<grid2(40, 40, NC), blk, 0, stream>>>(L5, b30, 40, 40, 1.4f);
    blur_kernel<9><<<grid2(10, 10, NC), blk, 0, stream>>>(L7, b150, 10, 10, 1.7f);
    blur_kernel<9><<<grid2(5,  5,  NC), blk, 0, stream>>>(L8, b300, 5, 5, 1.7f);

    // ---- upsample chains ----
    up2_kernel<<<grid2(10, 10, 1 * NC), blk, 0, stream>>>(b300, nullptr, nullptr,
                                                          u300_10, nullptr, nullptr, 5, 5);
    up2_kernel<<<grid2(20, 20, 2 * NC), blk, 0, stream>>>(b150, u300_10, nullptr,
                                                          u150_20, u300_20, nullptr, 10, 10);
    up2_kernel<<<grid2(40, 40, 2 * NC), blk, 0, stream>>>(u150_20, u300_20, nullptr,
                                                          u150_40, u300_40, nullptr, 20, 20);
    up2_kernel<<<grid2(80, 80, 3 * NC), blk, 0, stream>>>(b30, u150_40, u300_40,
                                                          u30_80, u150_80, u300_80, 40, 40);
    up2_kernel<<<grid2(160, 160, 3 * NC), blk, 0, stream>>>(u30_80, u150_80, u300_80,
                                                            u30_160, u150_160, u300_160, 80, 80);
    up2_kernel<<<grid2(320, 320, 3 * NC), blk, 0, stream>>>(u30_160, u150_160, u300_160,
                                                            u30_320, u150_320, u300_320, 160, 160);

    // ---- fused final ----
    final_kernel<<<dim3(3200, 1, 1), dim3(256, 1, 1), 0, stream>>>(x, u30_320, u150_320, u300_320, out);
}